// Round 2
// baseline (736.618 us; speedup 1.0000x reference)
//
#include <hip/hip_runtime.h>
#include <math.h>

// TopK router: B=4,S=4096,D=2048,E=64,K=2
// logits = x[16384,2048] @ w[64,2048]^T ; softmax; top-2 + renorm
// out (f32 flat): idx[16384*2] | topk_probs[16384*2] | probs[16384*64]
//
// Structure: lane = expert (E == wavefront 64). Wave owns T=8 tokens.
// w streamed through LDS (double-buffered, b128 reads, conflict-free);
// x is wave-uniform -> uniform vector loads, 2-deep prefetch pipeline.
// Epilogue: shuffle-reduce argmax/2nd-max/sum across 64 lanes.

#define TOK   16384
#define DD    2048
#define EE    64
#define BK    64
#define NCH   (DD / BK)     // 32
#define TW    8             // tokens per wave
#define NWAVE 4
#define BMT   (TW * NWAVE)  // 32 tokens per block
#define NBLK  (TOK / BMT)   // 512 blocks -> 2 blocks/CU

#define OUT_TP    (TOK * 2)
#define OUT_PROBS (TOK * 4)

__global__ __launch_bounds__(256, 4)
void router_v2(const float* __restrict__ x, const float* __restrict__ w,
               float* __restrict__ out) {
    // wt4[buf][kg][e][j] = w[e][c*BK + kg*4 + j]   (32 KiB)
    __shared__ float wt4[2][BK / 4][EE][4];

    const int tid  = threadIdx.x;
    const int lane = tid & 63;
    const int wid  = __builtin_amdgcn_readfirstlane(tid >> 6);
    const int g0   = blockIdx.x * BMT;
    const int tb   = g0 + wid * TW;           // wave's first token (uniform)

    // w staging map: thread -> expert row se, 16-float segment sq
    const int se = tid >> 2;                  // 0..63
    const int sq = tid & 3;                   // 0..3
    const float* wrow = w + (size_t)se * DD + sq * 16;

    // wave-uniform x row pointers
    const float* xr[TW];
#pragma unroll
    for (int t = 0; t < TW; ++t) xr[t] = x + (size_t)(tb + t) * DD;

    float acc[TW];
#pragma unroll
    for (int t = 0; t < TW; ++t) acc[t] = 0.f;

    // ---- prologue: stage w chunk 0 into buf 0 ----
    float4 nw[4];
#pragma unroll
    for (int r = 0; r < 4; ++r) nw[r] = *(const float4*)(wrow + r * 4);
#pragma unroll
    for (int r = 0; r < 4; ++r)
        *(float4*)&wt4[0][sq * 4 + r][se][0] = nw[r];

    // x prefetch pipeline: slot kg&1 holds x for current kg, refilled 2 ahead
    float4 xf[2][TW];
#pragma unroll
    for (int t = 0; t < TW; ++t) xf[0][t] = *(const float4*)(xr[t] + 0);
#pragma unroll
    for (int t = 0; t < TW; ++t) xf[1][t] = *(const float4*)(xr[t] + 4);

    __syncthreads();

    int buf = 0;
#pragma unroll 1
    for (int c = 0; c < NCH; ++c) {
        // T14: issue next w-chunk global loads early (land during compute)
        if (c + 1 < NCH) {
            const float* wp = wrow + (c + 1) * BK;
#pragma unroll
            for (int r = 0; r < 4; ++r) nw[r] = *(const float4*)(wp + r * 4);
        }

        // hand-pipelined w fragment (depth 1 in LDS reads)
        float4 wvA = *(const float4*)&wt4[buf][0][lane][0];
#pragma unroll
        for (int kg = 0; kg < BK / 4; ++kg) {
            float4 wvB;
            if (kg + 1 < BK / 4)
                wvB = *(const float4*)&wt4[buf][kg + 1][lane][0];

#pragma unroll
            for (int t = 0; t < TW; ++t) {
                float4 xv = xf[kg & 1][t];
                acc[t] = fmaf(xv.x, wvA.x, acc[t]);
                acc[t] = fmaf(xv.y, wvA.y, acc[t]);
                acc[t] = fmaf(xv.z, wvA.z, acc[t]);
                acc[t] = fmaf(xv.w, wvA.w, acc[t]);
            }

            // refill x slot for (this kg + 2), crosses chunk boundary
            const int knext = c * BK + kg * 4 + 8;
            if (knext < DD) {
#pragma unroll
                for (int t = 0; t < TW; ++t)
                    xf[kg & 1][t] = *(const float4*)(xr[t] + knext);
            }
            wvA = wvB;
        }

        // late ds_write of the prefetched w chunk, then one barrier
        if (c + 1 < NCH) {
#pragma unroll
            for (int r = 0; r < 4; ++r)
                *(float4*)&wt4[buf ^ 1][sq * 4 + r][se][0] = nw[r];
        }
        __syncthreads();
        buf ^= 1;
    }

    // ---- epilogue: per token, cross-lane top-2 / softmax ----
#pragma unroll
    for (int t = 0; t < TW; ++t) {
        const float v = acc[t];

        // argmax, min-index tie-break (matches jax.lax.top_k)
        float m1 = v; int i1 = lane;
#pragma unroll
        for (int s = 32; s > 0; s >>= 1) {
            float ov = __shfl_xor(m1, s, 64);
            int   oi = __shfl_xor(i1, s, 64);
            if (ov > m1 || (ov == m1 && oi < i1)) { m1 = ov; i1 = oi; }
        }
        // second max: mask out i1
        float m2 = (lane == i1) ? -INFINITY : v; int i2 = lane;
#pragma unroll
        for (int s = 32; s > 0; s >>= 1) {
            float ov = __shfl_xor(m2, s, 64);
            int   oi = __shfl_xor(i2, s, 64);
            if (ov > m2 || (ov == m2 && oi < i2)) { m2 = ov; i2 = oi; }
        }

        float e = __expf(v - m1);
        float ssum = e;
#pragma unroll
        for (int s = 32; s > 0; s >>= 1) ssum += __shfl_xor(ssum, s, 64);
        const float inv = 1.f / ssum;

        const size_t g = (size_t)(tb + t);
        out[OUT_PROBS + g * EE + lane] = e * inv;

        if (lane == 0) {
            float p1 = inv;                    // exp(m1-m1)*inv
            float p2 = __expf(m2 - m1) * inv;
            float den = p1 + p2 + 1e-9f;
            out[g * 2 + 0] = (float)i1;
            out[g * 2 + 1] = (float)i2;
            out[OUT_TP + g * 2 + 0] = p1 / den;
            out[OUT_TP + g * 2 + 1] = p2 / den;
        }
    }
}

extern "C" void kernel_launch(void* const* d_in, const int* in_sizes, int n_in,
                              void* d_out, int out_size, void* d_ws, size_t ws_size,
                              hipStream_t stream) {
    const float* x = (const float*)d_in[0];   // [4,4096,2048] f32
    const float* w = (const float*)d_in[1];   // [64,2048] f32
    router_v2<<<NBLK, 256, 0, stream>>>(x, w, (float*)d_out);
}

// Round 3
// 315.267 us; speedup vs baseline: 2.3365x; 2.3365x over previous
//
#include <hip/hip_runtime.h>
#include <math.h>

// TopK router: logits = x[16384,2048] @ w[64,2048]^T ; softmax; top-2 + renorm
// out (f32 flat): idx[32768] | topk_probs[32768] | probs[16384*64]
//
// v3: 4x4 register-tile fp32 GEMM, x+w staged via global_load_lds (double
// buffered, XOR-swizzled SOURCE so ds_read fragments are conflict-free),
// K split 2-way across blocks (2 blocks/CU), partial logits atomicAdd'ed
// into the probs region, then a finalize kernel does softmax/top-2.

#define TOK    16384
#define DD     2048
#define EE     64
#define BM     64
#define BK     64
#define KSPLIT 2
#define KHALF  (DD / KSPLIT)      // 1024
#define NCH    (KHALF / BK)       // 16 chunks per block

#define OUT_TP    (TOK * 2)
#define OUT_PROBS (TOK * 4)

typedef unsigned int u32;
typedef __attribute__((address_space(3))) u32 lds_u32;
typedef const __attribute__((address_space(1))) u32 glb_u32;

static __device__ __forceinline__ void gload16(const float* g, float* l) {
    __builtin_amdgcn_global_load_lds((glb_u32*)(const void*)g,
                                     (lds_u32*)(void*)l, 16, 0, 0);
}

__global__ __launch_bounds__(256, 2)
void gemm_part(const float* __restrict__ x, const float* __restrict__ w,
               float* __restrict__ out) {
    // granule p (16B) at byte p*16 holds logical (row r = p>>4, quad q = (p&15)^(r&7))
    __shared__ float xs[2][BM * BK];
    __shared__ float ws[2][EE * BK];

    const int tid = threadIdx.x;
    const int mb  = blockIdx.x >> 1;
    const int kh  = blockIdx.x & 1;
    const int g0  = mb * BM;
    const int k0  = kh * KHALF;
    const int tx  = tid & 15;            // expert group
    const int ty  = tid >> 4;            // token group

    // staging source map: 4 granules per thread per operand per chunk
    int sr[4], sq[4];
#pragma unroll
    for (int it = 0; it < 4; ++it) {
        int p  = it * 256 + tid;
        sr[it] = p >> 4;
        sq[it] = ((p & 15) ^ (sr[it] & 7)) * 4;   // float offset within row
    }

    // read bases: byte = (r<<8) ^ ((r&7)<<4), then ^ (kg<<4) per k-group
    int xb[4], wb[4];
#pragma unroll
    for (int i = 0; i < 4; ++i) {
        int rx = ty * 4 + i;
        xb[i]  = (rx << 8) ^ ((rx & 7) << 4);
        int re = tx * 4 + i;
        wb[i]  = (re << 8) ^ ((re & 7) << 4);
    }

    float acc[4][4] = {{0.f}};

#define STAGE(buf, c)                                                        \
    {                                                                        \
        const int kk = k0 + (c) * BK;                                        \
        _Pragma("unroll")                                                    \
        for (int it = 0; it < 4; ++it) {                                     \
            gload16(x + (size_t)(g0 + sr[it]) * DD + kk + sq[it],            \
                    &xs[buf][(it * 256 + tid) * 4]);                         \
            gload16(w + (size_t)sr[it] * DD + kk + sq[it],                   \
                    &ws[buf][(it * 256 + tid) * 4]);                         \
        }                                                                    \
    }

    STAGE(0, 0)
    __syncthreads();

    int buf = 0;
#pragma unroll 1
    for (int c = 0; c < NCH; ++c) {
        if (c + 1 < NCH) STAGE(buf ^ 1, c + 1)

        const char* xbase = (const char*)&xs[buf][0];
        const char* wbase = (const char*)&ws[buf][0];
#pragma unroll
        for (int kg = 0; kg < BK / 4; ++kg) {
            float4 xv[4], wu[4];
#pragma unroll
            for (int i = 0; i < 4; ++i)
                xv[i] = *(const float4*)(xbase + (xb[i] ^ (kg << 4)));
#pragma unroll
            for (int j = 0; j < 4; ++j)
                wu[j] = *(const float4*)(wbase + (wb[j] ^ (kg << 4)));
#pragma unroll
            for (int i = 0; i < 4; ++i)
#pragma unroll
                for (int j = 0; j < 4; ++j) {
                    acc[i][j] = fmaf(xv[i].x, wu[j].x, acc[i][j]);
                    acc[i][j] = fmaf(xv[i].y, wu[j].y, acc[i][j]);
                    acc[i][j] = fmaf(xv[i].z, wu[j].z, acc[i][j]);
                    acc[i][j] = fmaf(xv[i].w, wu[j].w, acc[i][j]);
                }
        }
        __syncthreads();
        buf ^= 1;
    }

    // accumulate partial logits into probs region (zeroed by memsetAsync)
    float* L = out + OUT_PROBS;
#pragma unroll
    for (int i = 0; i < 4; ++i)
#pragma unroll
        for (int j = 0; j < 4; ++j)
            atomicAdd(&L[(size_t)(g0 + ty * 4 + i) * EE + tx * 4 + j], acc[i][j]);
}

// finalize: per wave 8 tokens; lane = expert; shuffle top-2/softmax; in-place
__global__ __launch_bounds__(256, 4)
void finalize(float* __restrict__ out) {
    const int tid  = threadIdx.x;
    const int lane = tid & 63;
    const int wid  = tid >> 6;
    const int tb   = blockIdx.x * 32 + wid * 8;
    float* L = out + OUT_PROBS;

#pragma unroll
    for (int t = 0; t < 8; ++t) {
        const size_t g = (size_t)(tb + t);
        const float v = L[g * EE + lane];

        float m1 = v; int i1 = lane;
#pragma unroll
        for (int s = 32; s > 0; s >>= 1) {
            float ov = __shfl_xor(m1, s, 64);
            int   oi = __shfl_xor(i1, s, 64);
            if (ov > m1 || (ov == m1 && oi < i1)) { m1 = ov; i1 = oi; }
        }
        float m2 = (lane == i1) ? -INFINITY : v; int i2 = lane;
#pragma unroll
        for (int s = 32; s > 0; s >>= 1) {
            float ov = __shfl_xor(m2, s, 64);
            int   oi = __shfl_xor(i2, s, 64);
            if (ov > m2 || (ov == m2 && oi < i2)) { m2 = ov; i2 = oi; }
        }

        float e = __expf(v - m1);
        float ssum = e;
#pragma unroll
        for (int s = 32; s > 0; s >>= 1) ssum += __shfl_xor(ssum, s, 64);
        const float inv = 1.f / ssum;

        L[g * EE + lane] = e * inv;

        if (lane == 0) {
            float p1 = inv;
            float p2 = __expf(m2 - m1) * inv;
            float den = p1 + p2 + 1e-9f;
            out[g * 2 + 0] = (float)i1;
            out[g * 2 + 1] = (float)i2;
            out[OUT_TP + g * 2 + 0] = p1 / den;
            out[OUT_TP + g * 2 + 1] = p2 / den;
        }
    }
}

extern "C" void kernel_launch(void* const* d_in, const int* in_sizes, int n_in,
                              void* d_out, int out_size, void* d_ws, size_t ws_size,
                              hipStream_t stream) {
    const float* x = (const float*)d_in[0];   // [4,4096,2048] f32
    const float* w = (const float*)d_in[1];   // [64,2048] f32
    float* out = (float*)d_out;

    hipMemsetAsync(out + OUT_PROBS, 0, (size_t)TOK * EE * sizeof(float), stream);
    gemm_part<<<(TOK / BM) * KSPLIT, 256, 0, stream>>>(x, w, out);
    finalize<<<TOK / 32, 256, 0, stream>>>(out);
}